// Round 2
// baseline (565.171 us; speedup 1.0000x reference)
//
#include <hip/hip_runtime.h>
#include <hip/hip_bf16.h>
#include <stdint.h>

// ---------- types ----------
typedef __bf16 bf16x8 __attribute__((ext_vector_type(8)));
typedef float  f32x4  __attribute__((ext_vector_type(4)));
typedef uint16_t u16x8 __attribute__((ext_vector_type(8)));

__device__ __forceinline__ uint16_t f32_to_bf16(float f) {
    union { float f; uint32_t u; } v; v.f = f;
    uint32_t u = v.u;
    uint32_t r = (u + 0x7FFFu + ((u >> 16) & 1u)) >> 16;
    return (uint16_t)r;
}

// async global->LDS, 16B per lane. LDS dest semantics: wave-uniform base + lane*16.
__device__ __forceinline__ void gld16(const void* g, void* l) {
    __builtin_amdgcn_global_load_lds(
        (const __attribute__((address_space(1))) void*)g,
        (__attribute__((address_space(3))) void*)l,
        16, 0, 0);
}

#define MFMA16 __builtin_amdgcn_mfma_f32_16x16x32_bf16
#define SBAR   __builtin_amdgcn_s_barrier
#define SCHED0() __builtin_amdgcn_sched_barrier(0)
#define PRIO   __builtin_amdgcn_s_setprio

// ---------- fp32 -> bf16 casts for q,k,v in one launch; 8 floats/thread ----------
__global__ __launch_bounds__(256) void cast3_kernel(
    const float* __restrict__ i0, const float* __restrict__ i1,
    const float* __restrict__ i2, uint16_t* __restrict__ o0,
    uint16_t* __restrict__ o1, uint16_t* __restrict__ o2) {
    const float* in = (blockIdx.z == 0) ? i0 : (blockIdx.z == 1) ? i1 : i2;
    uint16_t* out = (blockIdx.z == 0) ? o0 : (blockIdx.z == 1) ? o1 : o2;
    size_t i = ((size_t)blockIdx.x * 256 + threadIdx.x) * 8;
    float4 a = *(const float4*)(in + i);
    float4 b = *(const float4*)(in + i + 4);
    u16x8 o;
    o[0] = f32_to_bf16(a.x); o[1] = f32_to_bf16(a.y);
    o[2] = f32_to_bf16(a.z); o[3] = f32_to_bf16(a.w);
    o[4] = f32_to_bf16(b.x); o[5] = f32_to_bf16(b.y);
    o[6] = f32_to_bf16(b.z); o[7] = f32_to_bf16(b.w);
    *(u16x8*)(out + i) = o;
}

// ---------- W [K=1024][N=1024] f32 -> Wt [N][K] bf16, 3 weights via grid.z ----------
__global__ __launch_bounds__(256) void wtrans_kernel(
    const float* __restrict__ W0, const float* __restrict__ W1,
    const float* __restrict__ W2, uint16_t* __restrict__ Wt0) {
    const float* W = (blockIdx.z == 0) ? W0 : (blockIdx.z == 1) ? W1 : W2;
    uint16_t* Wt = Wt0 + (size_t)blockIdx.z * 1024 * 1024;
    __shared__ float tile[64][65];
    const int n0 = blockIdx.x * 64, k0 = blockIdx.y * 64;
    const int tx = threadIdx.x & 63, ty0 = threadIdx.x >> 6;
#pragma unroll
    for (int r = 0; r < 16; ++r) {
        int ty = ty0 + r * 4;
        tile[ty][tx] = W[(size_t)(k0 + ty) * 1024 + n0 + tx];
    }
    __syncthreads();
#pragma unroll
    for (int r = 0; r < 16; ++r) {
        int ty = ty0 + r * 4;
        Wt[(size_t)(n0 + ty) * 1024 + k0 + tx] = f32_to_bf16(tile[tx][ty]);
    }
}

// ============================================================================
// 256x256x(BK=64) NT GEMM core, 512 threads = 8 waves (2 M x 4 N), 8-phase-
// style schedule (T2 swizzle + per-phase interleave + counted-cover prefetch
// + setprio). LDS: 2 double-buffered 256x64 bf16 tiles for A and B = 128 KiB.
//
// LDS layout per tile: row-major [256][64] bf16 (128B rows), staged linearly
// by gld_lds (thread t of issue i -> byte i*8192 + t*16). Swizzle: 16B chunk
// c within a row holds global chunk (c ^ (row&7)) -- applied on the GLOBAL
// source address at stage time and on the ds_read address at use time
// (both-sides-or-neither). Bijective per row.
// ============================================================================
__device__ __forceinline__ void stage_tile(const uint16_t* __restrict__ G,
                                           int ldg, int k0,
                                           uint16_t* lds, int tid) {
    const int r = tid >> 3, ch = tid & 7;
    const int c = ((ch ^ (r & 7)) << 3);  // swizzled source chunk (elems)
#pragma unroll
    for (int i = 0; i < 4; ++i) {
        const int row = i * 64 + r;
        gld16(G + (size_t)row * ldg + k0 + c, lds + i * 4096 + tid * 8);
    }
}

__device__ __forceinline__ void gemm_core(const uint16_t* __restrict__ A, int lda,
                                          const uint16_t* __restrict__ B, int ldb,
                                          int K, f32x4 (&acc)[8][4]) {
    __shared__ __align__(16) uint16_t As[2][16384];
    __shared__ __align__(16) uint16_t Bs[2][16384];
    const int tid  = threadIdx.x;
    const int lane = tid & 63;
    const int wave = tid >> 6;
    const int wr = wave >> 2, wcn = wave & 3;   // wave tile: rows wr*128, cols wcn*64
    const int mrow = lane & 15, q = lane >> 4;
    const int sx = mrow & 7;                     // row&7 is mrow&7 for all frags
    const int abase = (wr * 128 + mrow) * 64;    // elems
    const int bbase = (wcn * 64 + mrow) * 64;
    const int c0 = ((q ^ sx) << 3);              // kk=0 swizzled chunk offset
    const int c1 = (((4 + q) ^ sx) << 3);        // kk=1

    // prologue: stage K-tile 0 into buffer 0, full drain once.
    stage_tile(A, lda, 0, As[0], tid);
    stage_tile(B, ldb, 0, Bs[0], tid);
    __syncthreads();

    const int NT = K >> 6;
    bf16x8 af[4][2], bA[2][2], bB[2][2];
    for (int t = 0; t < NT; ++t) {
        const int cur = t & 1;
        const uint16_t* as = As[cur];
        const uint16_t* bs = Bs[cur];
        const int kn = (t + 1) << 6;
        const bool pf = (t + 1 < NT);

        // ---- phase 1: prefetch next A; read A(m0-3), B(n0-1); MFMA quadrant
        if (pf) stage_tile(A, lda, kn, As[cur ^ 1], tid);
#pragma unroll
        for (int m = 0; m < 4; ++m) {
            af[m][0] = *(const bf16x8*)&as[abase + m * 1024 + c0];
            af[m][1] = *(const bf16x8*)&as[abase + m * 1024 + c1];
        }
#pragma unroll
        for (int n = 0; n < 2; ++n) {
            bA[n][0] = *(const bf16x8*)&bs[bbase + n * 1024 + c0];
            bA[n][1] = *(const bf16x8*)&bs[bbase + n * 1024 + c1];
        }
        SBAR(); SCHED0();
        PRIO(1);
#pragma unroll
        for (int m = 0; m < 4; ++m)
#pragma unroll
            for (int n = 0; n < 2; ++n) {
                acc[m][n] = MFMA16(af[m][0], bA[n][0], acc[m][n], 0, 0, 0);
                acc[m][n] = MFMA16(af[m][1], bA[n][1], acc[m][n], 0, 0, 0);
            }
        PRIO(0);
        SBAR(); SCHED0();

        // ---- phase 2: prefetch next B; read B(n2-3); MFMA quadrant
        if (pf) stage_tile(B, ldb, kn, Bs[cur ^ 1], tid);
#pragma unroll
        for (int n = 0; n < 2; ++n) {
            bB[n][0] = *(const bf16x8*)&bs[bbase + (n + 2) * 1024 + c0];
            bB[n][1] = *(const bf16x8*)&bs[bbase + (n + 2) * 1024 + c1];
        }
        SBAR(); SCHED0();
        PRIO(1);
#pragma unroll
        for (int m = 0; m < 4; ++m)
#pragma unroll
            for (int n = 0; n < 2; ++n) {
                acc[m][n + 2] = MFMA16(af[m][0], bB[n][0], acc[m][n + 2], 0, 0, 0);
                acc[m][n + 2] = MFMA16(af[m][1], bB[n][1], acc[m][n + 2], 0, 0, 0);
            }
        PRIO(0);
        SBAR(); SCHED0();

        // ---- phase 3+4: read A(m4-7); MFMA two quadrants (no more LDS reads)
#pragma unroll
        for (int m = 0; m < 4; ++m) {
            af[m][0] = *(const bf16x8*)&as[abase + (m + 4) * 1024 + c0];
            af[m][1] = *(const bf16x8*)&as[abase + (m + 4) * 1024 + c1];
        }
        SBAR(); SCHED0();
        PRIO(1);
#pragma unroll
        for (int m = 0; m < 4; ++m)
#pragma unroll
            for (int n = 0; n < 2; ++n) {
                acc[m + 4][n + 2] = MFMA16(af[m][0], bB[n][0], acc[m + 4][n + 2], 0, 0, 0);
                acc[m + 4][n + 2] = MFMA16(af[m][1], bB[n][1], acc[m + 4][n + 2], 0, 0, 0);
            }
#pragma unroll
        for (int m = 0; m < 4; ++m)
#pragma unroll
            for (int n = 0; n < 2; ++n) {
                acc[m + 4][n] = MFMA16(af[m][0], bA[n][0], acc[m + 4][n], 0, 0, 0);
                acc[m + 4][n] = MFMA16(af[m][1], bA[n][1], acc[m + 4][n], 0, 0, 0);
            }
        PRIO(0);
        // K-tile boundary: drains vmcnt (prefetch issued 2.5-3.5 phases ago ->
        // near-zero stall) and protects both LDS buffers across the swap.
        __syncthreads();
    }
}

// ---------- merged projection GEMM (q,k,v), 256x256 tiles ----------
// grid 768 = 3 proj x 64 Mt x 4 Nt. V (pidx 2) written transposed to Vt[b][d][s].
__global__ __launch_bounds__(512, 2) void proj256_kernel(
    const uint16_t* __restrict__ Ab, const uint16_t* __restrict__ Bb,
    uint16_t* __restrict__ Cb, uint16_t* __restrict__ Vt,
    const float* __restrict__ b0, const float* __restrict__ b1,
    const float* __restrict__ b2) {
    const int bid = blockIdx.x;
    const int lg = (bid & 7) * 96 + (bid >> 3);   // bijective XCD chunk swizzle
    const int pidx = lg >> 8;
    const int t = lg & 255;
    const int band = t >> 4;                       // bands of 4 Mt x 4 Nt
    const int Mt = band * 4 + (t & 3);
    const int Nt = (t >> 2) & 3;
    const int row0 = Mt * 256, col0 = Nt * 256;

    const uint16_t* A = Ab + (size_t)pidx * 16777216 + (size_t)row0 * 1024;
    const uint16_t* B = Bb + (size_t)pidx * 1048576 + (size_t)col0 * 1024;
    const float* bias = (pidx == 0) ? b0 : (pidx == 1) ? b1 : b2;

    f32x4 acc[8][4];
#pragma unroll
    for (int i = 0; i < 8; ++i)
#pragma unroll
        for (int j = 0; j < 4; ++j) acc[i][j] = 0.0f;

    gemm_core(A, 1024, B, 1024, 1024, acc);

    const int tid = threadIdx.x, lane = tid & 63, wave = tid >> 6;
    const int wr = wave >> 2, wcn = wave & 3;
    const int mrow = lane & 15, quad = lane >> 4;
    float bv_[4];
#pragma unroll
    for (int n = 0; n < 4; ++n) bv_[n] = bias[col0 + wcn * 64 + n * 16 + mrow];

    if (pidx < 2) {
        uint16_t* C = Cb + (size_t)pidx * 16777216;
#pragma unroll
        for (int m = 0; m < 8; ++m)
#pragma unroll
            for (int n = 0; n < 4; ++n)
#pragma unroll
                for (int r = 0; r < 4; ++r) {
                    int row = row0 + wr * 128 + m * 16 + quad * 4 + r;
                    int col = col0 + wcn * 64 + n * 16 + mrow;
                    C[(size_t)row * 1024 + col] = f32_to_bf16(acc[m][n][r] + bv_[n]);
                }
    } else {
#pragma unroll
        for (int m = 0; m < 8; ++m)
#pragma unroll
            for (int n = 0; n < 4; ++n)
#pragma unroll
                for (int r = 0; r < 4; ++r) {
                    int row = row0 + wr * 128 + m * 16 + quad * 4 + r;
                    int col = col0 + wcn * 64 + n * 16 + mrow;
                    Vt[((size_t)(row >> 11) * 1024 + col) * 2048 + (row & 2047)] =
                        f32_to_bf16(acc[m][n][r] + bv_[n]);
                }
    }
}

// ---------- batched NT GEMM, 256x256 tiles ----------
// EPI 1 = bf16 exp(alpha*acc) + per-row sum atomics (scores)
// EPI 2 = f32 acc / sums[row]                        (PV)
// chunk = blocks per XCD = blocks per z (grid = 8*chunk).
template <int EPI>
__global__ __launch_bounds__(512, 2) void att256_kernel(
    const uint16_t* __restrict__ Abase, int lda, long long sAz,
    const uint16_t* __restrict__ Bbase, int ldb, long long sBz,
    void* __restrict__ Cv, int ldc, long long sCz,
    int K, float alpha, float* __restrict__ sums, int NtN, int chunk) {
    const int bid = blockIdx.x;
    const int lg = (bid & 7) * chunk + (bid >> 3);  // bijective XCD chunk swizzle
    const int z = lg / chunk;                        // one z per XCD
    const int t = lg % chunk;
    const int r2 = t & (2 * NtN - 1);                // bands of 2 Mt x NtN
    const int band = t / (2 * NtN);
    const int Mt = band * 2 + (r2 & 1);
    const int Nt = r2 >> 1;
    const int row0 = Mt * 256, col0 = Nt * 256;

    const uint16_t* A = Abase + (size_t)z * sAz + (size_t)row0 * lda;
    const uint16_t* B = Bbase + (size_t)z * sBz + (size_t)col0 * ldb;

    f32x4 acc[8][4];
#pragma unroll
    for (int i = 0; i < 8; ++i)
#pragma unroll
        for (int j = 0; j < 4; ++j) acc[i][j] = 0.0f;

    gemm_core(A, lda, B, ldb, K, acc);

    const int tid = threadIdx.x, lane = tid & 63, wave = tid >> 6;
    const int wr = wave >> 2, wcn = wave & 3;
    const int mrow = lane & 15, quad = lane >> 4;

    if (EPI == 1) {
        // unnormalized exp scores + row-sum atomics (softmax shift-invariant,
        // scores ~ N(0,1) -> no max subtraction needed at fp32).
        uint16_t* C = (uint16_t*)Cv + (size_t)z * sCz;
#pragma unroll
        for (int m = 0; m < 8; ++m)
#pragma unroll
            for (int r = 0; r < 4; ++r) {
                int row = row0 + wr * 128 + m * 16 + quad * 4 + r;
                float s = 0.0f;
#pragma unroll
                for (int n = 0; n < 4; ++n) {
                    int col = col0 + wcn * 64 + n * 16 + mrow;
                    float e = __expf(acc[m][n][r] * alpha);
                    C[(size_t)row * ldc + col] = f32_to_bf16(e);
                    s += e;
                }
                s += __shfl_xor(s, 1, 64);
                s += __shfl_xor(s, 2, 64);
                s += __shfl_xor(s, 4, 64);
                s += __shfl_xor(s, 8, 64);
                if (mrow == 0) atomicAdd(&sums[(size_t)z * 2048 + row], s);
            }
    } else {
        float* C = (float*)Cv + (size_t)z * sCz;
#pragma unroll
        for (int m = 0; m < 8; ++m)
#pragma unroll
            for (int r = 0; r < 4; ++r) {
                int row = row0 + wr * 128 + m * 16 + quad * 4 + r;
                float inv = 1.0f / sums[(size_t)z * 2048 + row];
#pragma unroll
                for (int n = 0; n < 4; ++n) {
                    int col = col0 + wcn * 64 + n * 16 + mrow;
                    C[(size_t)row * ldc + col] = acc[m][n][r] * inv;
                }
            }
    }
}

// ---------- launch ----------
extern "C" void kernel_launch(void* const* d_in, const int* in_sizes, int n_in,
                              void* d_out, int out_size, void* d_ws, size_t ws_size,
                              hipStream_t stream) {
    const float* in_k = (const float*)d_in[0];
    const float* in_q = (const float*)d_in[1];
    const float* in_v = (const float*)d_in[2];
    const float* Wk = (const float*)d_in[3];
    const float* bk = (const float*)d_in[4];
    const float* Wq = (const float*)d_in[5];
    const float* bq = (const float*)d_in[6];
    const float* Wv = (const float*)d_in[7];
    const float* bv = (const float*)d_in[8];
    float* out = (float*)d_out;

    // ws layout (bytes). Total: 198 MB.
    char* w = (char*)d_ws;
    uint16_t* Xq  = (uint16_t*)(w + 0);            // 32 MB (dead after proj -> Sc lo)
    uint16_t* Xk  = (uint16_t*)(w + 33554432);     // 32 MB (dead after proj -> Sc hi)
    uint16_t* Xv  = (uint16_t*)(w + 67108864);     // 32 MB (dead after proj -> sums)
    uint16_t* Qb  = (uint16_t*)(w + 100663296);    // 32 MB
    uint16_t* Kb  = (uint16_t*)(w + 134217728);    // 32 MB (contiguous with Qb)
    uint16_t* Vt  = (uint16_t*)(w + 167772160);    // 32 MB [b][1024][2048]
    uint16_t* Wqt = (uint16_t*)(w + 201326592);    // 2 MB (Wkt, Wvt follow)
    uint16_t* Sc  = Xq;                            // 64 MB overlay (Xq+Xk)
    float*    sums = (float*)Xv;                   // 64 KB overlay (dead Xv)

    // 1. weight transposes + input casts
    wtrans_kernel<<<dim3(16, 16, 3), 256, 0, stream>>>(Wq, Wk, Wv, Wqt);
    cast3_kernel<<<dim3(8192, 1, 3), 256, 0, stream>>>(in_q, in_k, in_v, Xq, Xk, Xv);

    // 2. merged projections (q,k,v); v written transposed into Vt
    proj256_kernel<<<768, 512, 0, stream>>>(Xq, Wqt, Qb, Vt, bq, bk, bv);

    // 3. zero row-sum buffer (overlays dead Xv)
    hipMemsetAsync(sums, 0, 8 * 2048 * sizeof(float), stream);

    // 4. scores + exp + row-sum: Sc[b] = exp((1/32) Q[b] @ K[b]^T)
    att256_kernel<1><<<512, 512, 0, stream>>>(
        Qb, 1024, 2048LL * 1024, Kb, 1024, 2048LL * 1024,
        Sc, 2048, 2048LL * 2048, 1024, 0.03125f, sums, 8, 64);

    // 5. out[b] = (P~[b] @ Vt[b]^T) / rowsum -> fp32
    att256_kernel<2><<<256, 512, 0, stream>>>(
        Sc, 2048, 2048LL * 2048, Vt, 2048, 1024LL * 2048,
        out, 1024, 2048LL * 1024, 2048, 1.0f, sums, 4, 32);
}

// Round 5
// 517.649 us; speedup vs baseline: 1.0918x; 1.0918x over previous
//
#include <hip/hip_runtime.h>
#include <hip/hip_bf16.h>
#include <stdint.h>

// ---------- types ----------
typedef __bf16 bf16x8 __attribute__((ext_vector_type(8)));
typedef float  f32x4  __attribute__((ext_vector_type(4)));
typedef uint16_t u16x8 __attribute__((ext_vector_type(8)));

__device__ __forceinline__ uint16_t f32_to_bf16(float f) {
    union { float f; uint32_t u; } v; v.f = f;
    uint32_t u = v.u;
    uint32_t r = (u + 0x7FFFu + ((u >> 16) & 1u)) >> 16;
    return (uint16_t)r;
}

// async global->LDS, 16B per lane. LDS dest semantics: wave-uniform base + lane*16.
__device__ __forceinline__ void gld16(const void* g, void* l) {
    __builtin_amdgcn_global_load_lds(
        (const __attribute__((address_space(1))) void*)g,
        (__attribute__((address_space(3))) void*)l,
        16, 0, 0);
}

#define MFMA16 __builtin_amdgcn_mfma_f32_16x16x32_bf16
#define SBAR   __builtin_amdgcn_s_barrier
#define SCHED0() __builtin_amdgcn_sched_barrier(0)
#define PRIO   __builtin_amdgcn_s_setprio
#define VMCNT4() asm volatile("s_waitcnt vmcnt(4)" ::: "memory")
#define VMCNT0() asm volatile("s_waitcnt vmcnt(0)" ::: "memory")

// ---------- fp32 -> bf16 casts for q,k,v in one launch; 8 floats/thread ----------
__global__ __launch_bounds__(256) void cast3_kernel(
    const float* __restrict__ i0, const float* __restrict__ i1,
    const float* __restrict__ i2, uint16_t* __restrict__ o0,
    uint16_t* __restrict__ o1, uint16_t* __restrict__ o2) {
    const float* in = (blockIdx.z == 0) ? i0 : (blockIdx.z == 1) ? i1 : i2;
    uint16_t* out = (blockIdx.z == 0) ? o0 : (blockIdx.z == 1) ? o1 : o2;
    size_t i = ((size_t)blockIdx.x * 256 + threadIdx.x) * 8;
    float4 a = *(const float4*)(in + i);
    float4 b = *(const float4*)(in + i + 4);
    u16x8 o;
    o[0] = f32_to_bf16(a.x); o[1] = f32_to_bf16(a.y);
    o[2] = f32_to_bf16(a.z); o[3] = f32_to_bf16(a.w);
    o[4] = f32_to_bf16(b.x); o[5] = f32_to_bf16(b.y);
    o[6] = f32_to_bf16(b.z); o[7] = f32_to_bf16(b.w);
    *(u16x8*)(out + i) = o;
}

// ---------- W [K=1024][N=1024] f32 -> Wt [N][K] bf16, 3 weights via grid.z ----------
__global__ __launch_bounds__(256) void wtrans_kernel(
    const float* __restrict__ W0, const float* __restrict__ W1,
    const float* __restrict__ W2, uint16_t* __restrict__ Wt0) {
    const float* W = (blockIdx.z == 0) ? W0 : (blockIdx.z == 1) ? W1 : W2;
    uint16_t* Wt = Wt0 + (size_t)blockIdx.z * 1024 * 1024;
    __shared__ float tile[64][65];
    const int n0 = blockIdx.x * 64, k0 = blockIdx.y * 64;
    const int tx = threadIdx.x & 63, ty0 = threadIdx.x >> 6;
#pragma unroll
    for (int r = 0; r < 16; ++r) {
        int ty = ty0 + r * 4;
        tile[ty][tx] = W[(size_t)(k0 + ty) * 1024 + n0 + tx];
    }
    __syncthreads();
#pragma unroll
    for (int r = 0; r < 16; ++r) {
        int ty = ty0 + r * 4;
        Wt[(size_t)(n0 + ty) * 1024 + k0 + tx] = f32_to_bf16(tile[tx][ty]);
    }
}

// ============================================================================
// 256x256x(BK=64) NT GEMM core, 512 threads = 8 waves (2M x 4N).
// 4-phase K-tile schedule with COUNTED vmcnt pipeline (T3+T4), T2 source-side
// XOR swizzle, T5 setprio. LDS: 2 dbuf x (A 256x64 + B 256x64) bf16 = 128 KiB.
//
// Half-tile staging, one half (2 gld_lds/wave = 64 LDS rows each) per phase,
// issue order Ah0,Bh0,Bh1,Ah1 per tile. B rows are PERMUTED in LDS so the
// rows all waves need first (n0-1 frags of each wcn group) occupy lrows
// 0..127 (= Bh0). vmcnt(4) per phase (never 0 in loop): waits only for the
// oldest half-tile, issued 3-4 phases (~600-900cyc) earlier. The K-tile
// boundary needs no drain at all.
//
// LDS dest is linear in tid (gld_lds constraint); both the row permutation
// (B) and the 16B-chunk XOR swizzle (key = ldsrow&7) are applied to the
// GLOBAL source address; ds_read applies the same XOR (both-sides, rule 21).
// ============================================================================
__device__ __forceinline__ void stageA64(const uint16_t* __restrict__ G, int ldg,
                                         int k0, int rowbase, uint16_t* ldsT, int tid) {
    const int l = tid >> 3;                    // lds row within 64-row group
    const int ch = tid & 7;
    const int c = ((ch ^ (l & 7)) << 3);       // swizzled source chunk (elems)
    gld16(G + (size_t)(rowbase + l) * ldg + k0 + c,
          ldsT + (size_t)(rowbase + l) * 64 + ch * 8);   // = base + tid*16B
}

__device__ __forceinline__ void stageB64(const uint16_t* __restrict__ G, int ldg,
                                         int k0, int h, int j, uint16_t* ldsT, int tid) {
    const int lloc = j * 64 + (tid >> 3);      // 0..127 within half h
    const int ch = tid & 7;
    const int grow = (lloc & 31) + ((lloc >> 5) << 6) + (h << 5);  // row permutation
    const int c = ((ch ^ (lloc & 7)) << 3);
    gld16(G + (size_t)grow * ldg + k0 + c,
          ldsT + (size_t)(h * 128 + lloc) * 64 + ch * 8); // = base + tid*16B
}

__device__ __forceinline__ void gemm_core(const uint16_t* __restrict__ A, int lda,
                                          const uint16_t* __restrict__ B, int ldb,
                                          int K, f32x4 (&acc)[8][4]) {
    __shared__ __align__(16) uint16_t As[2][16384];
    __shared__ __align__(16) uint16_t Bs[2][16384];
    const int tid  = threadIdx.x;
    const int lane = tid & 63;
    const int wave = tid >> 6;
    const int wr = wave >> 2, wcn = wave & 3;   // wave tile: rows wr*128, cols wcn*64
    const int mrow = lane & 15, q = lane >> 4;
    const int sx = mrow & 7;
    const int c0 = ((q ^ sx) << 3);              // kk=0 swizzled chunk offset
    const int c1 = (((4 + q) ^ sx) << 3);        // kk=1
    const int abase = (wr * 128 + mrow) * 64;    // A frag m at + m*1024
    const int bb    = (wcn * 32 + mrow) * 64;    // B frag n at + (n>>1)*8192 + (n&1)*1024

    const int NT = K >> 6;
    // prologue: tile 0, issue order Ah0, Bh0, Bh1, Ah1 (ledger anchor).
    stageA64(A, lda, 0, 0,   As[0], tid);
    stageA64(A, lda, 0, 128, As[0], tid);
    SCHED0();
    stageB64(B, ldb, 0, 0, 0, Bs[0], tid);
    stageB64(B, ldb, 0, 0, 1, Bs[0], tid);
    SCHED0();
    stageB64(B, ldb, 0, 1, 0, Bs[0], tid);
    stageB64(B, ldb, 0, 1, 1, Bs[0], tid);
    SCHED0();
    stageA64(A, lda, 0, 64,  As[0], tid);
    stageA64(A, lda, 0, 192, As[0], tid);
    SCHED0();

    bf16x8 af[4][2], bA[2][2], bB[2][2];
    for (int t = 0; t < NT; ++t) {
        const int cur = t & 1;
        const uint16_t* as = As[cur];
        const uint16_t* bs = Bs[cur];
        uint16_t* An = As[cur ^ 1];
        uint16_t* Bn = Bs[cur ^ 1];
        // last tile wrap-stages tile 0 (harmless; keeps vmcnt ledger uniform)
        const int kn = (t + 1 < NT) ? ((t + 1) << 6) : 0;

        // ---- phase 0: m0-3 x n0-1. needs Ah0(t),Bh0(t) = oldest 4. stage Ah0(t+1).
        VMCNT4();
        SBAR(); SCHED0();
        stageA64(A, lda, kn, 0,   An, tid);
        stageA64(A, lda, kn, 128, An, tid);
#pragma unroll
        for (int m = 0; m < 4; ++m) {
            af[m][0] = *(const bf16x8*)&as[abase + m * 1024 + c0];
            af[m][1] = *(const bf16x8*)&as[abase + m * 1024 + c1];
        }
#pragma unroll
        for (int n = 0; n < 2; ++n) {
            bA[n][0] = *(const bf16x8*)&bs[bb + n * 1024 + c0];
            bA[n][1] = *(const bf16x8*)&bs[bb + n * 1024 + c1];
        }
        SBAR(); SCHED0();
        PRIO(1);
#pragma unroll
        for (int m = 0; m < 4; ++m)
#pragma unroll
            for (int n = 0; n < 2; ++n) {
                acc[m][n] = MFMA16(af[m][0], bA[n][0], acc[m][n], 0, 0, 0);
                acc[m][n] = MFMA16(af[m][1], bA[n][1], acc[m][n], 0, 0, 0);
            }
        PRIO(0);

        // ---- phase 1: m0-3 x n2-3. needs Bh1(t) = oldest 2. stage Bh0(t+1).
        VMCNT4();
        SBAR(); SCHED0();
        stageB64(B, ldb, kn, 0, 0, Bn, tid);
        stageB64(B, ldb, kn, 0, 1, Bn, tid);
#pragma unroll
        for (int n = 0; n < 2; ++n) {
            bB[n][0] = *(const bf16x8*)&bs[bb + 8192 + n * 1024 + c0];
            bB[n][1] = *(const bf16x8*)&bs[bb + 8192 + n * 1024 + c1];
        }
        SBAR(); SCHED0();
        PRIO(1);
#pragma unroll
        for (int m = 0; m < 4; ++m)
#pragma unroll
            for (int n = 0; n < 2; ++n) {
                acc[m][n + 2] = MFMA16(af[m][0], bB[n][0], acc[m][n + 2], 0, 0, 0);
                acc[m][n + 2] = MFMA16(af[m][1], bB[n][1], acc[m][n + 2], 0, 0, 0);
            }
        PRIO(0);

        // ---- phase 2: m4-7 x n0-1. needs Ah1(t) = oldest 2. stage Bh1(t+1).
        VMCNT4();
        SBAR(); SCHED0();
        stageB64(B, ldb, kn, 1, 0, Bn, tid);
        stageB64(B, ldb, kn, 1, 1, Bn, tid);
#pragma unroll
        for (int m = 0; m < 4; ++m) {  // overwrite af with m4-7 (disjoint lifetime)
            af[m][0] = *(const bf16x8*)&as[abase + (m + 4) * 1024 + c0];
            af[m][1] = *(const bf16x8*)&as[abase + (m + 4) * 1024 + c1];
        }
        SBAR(); SCHED0();
        PRIO(1);
#pragma unroll
        for (int m = 0; m < 4; ++m)
#pragma unroll
            for (int n = 0; n < 2; ++n) {
                acc[m + 4][n] = MFMA16(af[m][0], bA[n][0], acc[m + 4][n], 0, 0, 0);
                acc[m + 4][n] = MFMA16(af[m][1], bA[n][1], acc[m + 4][n], 0, 0, 0);
            }
        PRIO(0);

        // ---- phase 3: m4-7 x n2-3. needs nothing new. stage Ah1(t+1).
        SBAR(); SCHED0();
        stageA64(A, lda, kn, 64,  An, tid);
        stageA64(A, lda, kn, 192, An, tid);
        SBAR(); SCHED0();
        PRIO(1);
#pragma unroll
        for (int m = 0; m < 4; ++m)
#pragma unroll
            for (int n = 0; n < 2; ++n) {
                acc[m + 4][n + 2] = MFMA16(af[m][0], bB[n][0], acc[m + 4][n + 2], 0, 0, 0);
                acc[m + 4][n + 2] = MFMA16(af[m][1], bB[n][1], acc[m + 4][n + 2], 0, 0, 0);
            }
        PRIO(0);
    }
    VMCNT0();  // drain stray wrap-stage loads once, outside the loop
}

// ---------- merged projection GEMM (q,k,v), 256x256 tiles ----------
// grid 768 = 3 proj x 64 Mt x 4 Nt. V (pidx 2) written transposed to Vt[b][d][s].
__global__ __launch_bounds__(512, 2) void proj256_kernel(
    const uint16_t* __restrict__ Ab, const uint16_t* __restrict__ Bb,
    uint16_t* __restrict__ Cb, uint16_t* __restrict__ Vt,
    const float* __restrict__ b0, const float* __restrict__ b1,
    const float* __restrict__ b2) {
    const int bid = blockIdx.x;
    const int lg = (bid & 7) * 96 + (bid >> 3);   // bijective XCD chunk swizzle
    const int pidx = lg >> 8;
    const int t = lg & 255;
    const int band = t >> 4;                       // bands of 4 Mt x 4 Nt
    const int Mt = band * 4 + (t & 3);
    const int Nt = (t >> 2) & 3;
    const int row0 = Mt * 256, col0 = Nt * 256;

    const uint16_t* A = Ab + (size_t)pidx * 16777216 + (size_t)row0 * 1024;
    const uint16_t* B = Bb + (size_t)pidx * 1048576 + (size_t)col0 * 1024;
    const float* bias = (pidx == 0) ? b0 : (pidx == 1) ? b1 : b2;

    f32x4 acc[8][4];
#pragma unroll
    for (int i = 0; i < 8; ++i)
#pragma unroll
        for (int j = 0; j < 4; ++j) acc[i][j] = 0.0f;

    gemm_core(A, 1024, B, 1024, 1024, acc);

    const int tid = threadIdx.x, lane = tid & 63, wave = tid >> 6;
    const int wr = wave >> 2, wcn = wave & 3;
    const int mrow = lane & 15, quad = lane >> 4;
    float bv_[4];
#pragma unroll
    for (int n = 0; n < 4; ++n) bv_[n] = bias[col0 + wcn * 64 + n * 16 + mrow];

    if (pidx < 2) {
        uint16_t* C = Cb + (size_t)pidx * 16777216;
#pragma unroll
        for (int m = 0; m < 8; ++m)
#pragma unroll
            for (int n = 0; n < 4; ++n)
#pragma unroll
                for (int r = 0; r < 4; ++r) {
                    int row = row0 + wr * 128 + m * 16 + quad * 4 + r;
                    int col = col0 + wcn * 64 + n * 16 + mrow;
                    C[(size_t)row * 1024 + col] = f32_to_bf16(acc[m][n][r] + bv_[n]);
                }
    } else {
#pragma unroll
        for (int m = 0; m < 8; ++m)
#pragma unroll
            for (int n = 0; n < 4; ++n)
#pragma unroll
                for (int r = 0; r < 4; ++r) {
                    int row = row0 + wr * 128 + m * 16 + quad * 4 + r;
                    int col = col0 + wcn * 64 + n * 16 + mrow;
                    Vt[((size_t)(row >> 11) * 1024 + col) * 2048 + (row & 2047)] =
                        f32_to_bf16(acc[m][n][r] + bv_[n]);
                }
    }
}

// ---------- batched NT GEMM, 256x256 tiles ----------
// EPI 1 = bf16 exp(alpha*acc) + per-row sum atomics (scores)
// EPI 2 = f32 acc / sums[row]                        (PV)
// chunk = blocks per XCD = blocks per z (grid = 8*chunk).
template <int EPI>
__global__ __launch_bounds__(512, 2) void att256_kernel(
    const uint16_t* __restrict__ Abase, int lda, long long sAz,
    const uint16_t* __restrict__ Bbase, int ldb, long long sBz,
    void* __restrict__ Cv, int ldc, long long sCz,
    int K, float alpha, float* __restrict__ sums, int NtN, int chunk) {
    const int bid = blockIdx.x;
    const int lg = (bid & 7) * chunk + (bid >> 3);  // bijective XCD chunk swizzle
    const int z = lg / chunk;                        // one z per XCD
    const int t = lg % chunk;
    const int r2 = t & (2 * NtN - 1);                // bands of 2 Mt x NtN
    const int band = t / (2 * NtN);
    const int Mt = band * 2 + (r2 & 1);
    const int Nt = r2 >> 1;
    const int row0 = Mt * 256, col0 = Nt * 256;

    const uint16_t* A = Abase + (size_t)z * sAz + (size_t)row0 * lda;
    const uint16_t* B = Bbase + (size_t)z * sBz + (size_t)col0 * ldb;

    f32x4 acc[8][4];
#pragma unroll
    for (int i = 0; i < 8; ++i)
#pragma unroll
        for (int j = 0; j < 4; ++j) acc[i][j] = 0.0f;

    gemm_core(A, lda, B, ldb, K, acc);

    const int tid = threadIdx.x, lane = tid & 63, wave = tid >> 6;
    const int wr = wave >> 2, wcn = wave & 3;
    const int mrow = lane & 15, quad = lane >> 4;

    if (EPI == 1) {
        // unnormalized exp scores + row-sum atomics (softmax shift-invariant,
        // scores ~ N(0,1) -> no max subtraction needed at fp32).
        uint16_t* C = (uint16_t*)Cv + (size_t)z * sCz;
#pragma unroll
        for (int m = 0; m < 8; ++m)
#pragma unroll
            for (int r = 0; r < 4; ++r) {
                int row = row0 + wr * 128 + m * 16 + quad * 4 + r;
                float s = 0.0f;
#pragma unroll
                for (int n = 0; n < 4; ++n) {
                    int col = col0 + wcn * 64 + n * 16 + mrow;
                    float e = __expf(acc[m][n][r] * alpha);
                    C[(size_t)row * ldc + col] = f32_to_bf16(e);
                    s += e;
                }
                s += __shfl_xor(s, 1, 64);
                s += __shfl_xor(s, 2, 64);
                s += __shfl_xor(s, 4, 64);
                s += __shfl_xor(s, 8, 64);
                if (mrow == 0) atomicAdd(&sums[(size_t)z * 2048 + row], s);
            }
    } else {
        float* C = (float*)Cv + (size_t)z * sCz;
#pragma unroll
        for (int m = 0; m < 8; ++m)
#pragma unroll
            for (int r = 0; r < 4; ++r) {
                int row = row0 + wr * 128 + m * 16 + quad * 4 + r;
                float inv = 1.0f / sums[(size_t)z * 2048 + row];
#pragma unroll
                for (int n = 0; n < 4; ++n) {
                    int col = col0 + wcn * 64 + n * 16 + mrow;
                    C[(size_t)row * ldc + col] = acc[m][n][r] * inv;
                }
            }
    }
}

// ---------- launch ----------
extern "C" void kernel_launch(void* const* d_in, const int* in_sizes, int n_in,
                              void* d_out, int out_size, void* d_ws, size_t ws_size,
                              hipStream_t stream) {
    const float* in_k = (const float*)d_in[0];
    const float* in_q = (const float*)d_in[1];
    const float* in_v = (const float*)d_in[2];
    const float* Wk = (const float*)d_in[3];
    const float* bk = (const float*)d_in[4];
    const float* Wq = (const float*)d_in[5];
    const float* bq = (const float*)d_in[6];
    const float* Wv = (const float*)d_in[7];
    const float* bv = (const float*)d_in[8];
    float* out = (float*)d_out;

    // ws layout (bytes). Total: 198 MB.
    char* w = (char*)d_ws;
    uint16_t* Xq  = (uint16_t*)(w + 0);            // 32 MB (dead after proj -> Sc lo)
    uint16_t* Xk  = (uint16_t*)(w + 33554432);     // 32 MB (dead after proj -> Sc hi)
    uint16_t* Xv  = (uint16_t*)(w + 67108864);     // 32 MB (dead after proj -> sums)
    uint16_t* Qb  = (uint16_t*)(w + 100663296);    // 32 MB
    uint16_t* Kb  = (uint16_t*)(w + 134217728);    // 32 MB (contiguous with Qb)
    uint16_t* Vt  = (uint16_t*)(w + 167772160);    // 32 MB [b][1024][2048]
    uint16_t* Wqt = (uint16_t*)(w + 201326592);    // 2 MB (Wkt, Wvt follow)
    uint16_t* Sc  = Xq;                            // 64 MB overlay (Xq+Xk)
    float*    sums = (float*)Xv;                   // 64 KB overlay (dead Xv)

    // 1. weight transposes + input casts
    wtrans_kernel<<<dim3(16, 16, 3), 256, 0, stream>>>(Wq, Wk, Wv, Wqt);
    cast3_kernel<<<dim3(8192, 1, 3), 256, 0, stream>>>(in_q, in_k, in_v, Xq, Xk, Xv);

    // 2. merged projections (q,k,v); v written transposed into Vt
    proj256_kernel<<<768, 512, 0, stream>>>(Xq, Wqt, Qb, Vt, bq, bk, bv);

    // 3. zero row-sum buffer (overlays dead Xv)
    hipMemsetAsync(sums, 0, 8 * 2048 * sizeof(float), stream);

    // 4. scores + exp + row-sum: Sc[b] = exp((1/32) Q[b] @ K[b]^T)
    att256_kernel<1><<<512, 512, 0, stream>>>(
        Qb, 1024, 2048LL * 1024, Kb, 1024, 2048LL * 1024,
        Sc, 2048, 2048LL * 2048, 1024, 0.03125f, sums, 8, 64);

    // 5. out[b] = (P~[b] @ Vt[b]^T) / rowsum -> fp32
    att256_kernel<2><<<256, 512, 0, stream>>>(
        Sc, 2048, 2048LL * 2048, Vt, 2048, 1024LL * 2048,
        out, 1024, 2048LL * 1024, 2048, 1.0f, sums, 4, 32);
}